// Round 1
// baseline (842.069 us; speedup 1.0000x reference)
//
#include <hip/hip_runtime.h>

#define NS 256   // n_state
#define MO 128   // n_obs
#define BB 64    // batch
#define TT 1024  // time steps
#define CCH 4    // chunks
#define LL (TT / CCH)  // 256 steps per chunk

// ---------------- small setup kernels ----------------

// KH = K @ H   (256x128 @ 128x256 -> 256x256)
__global__ void kh_kernel(const float* __restrict__ K, const float* __restrict__ H,
                          float* __restrict__ KH) {
    int i = blockIdx.x, j = threadIdx.x;
    __shared__ float kl[MO];
    if (j < MO) kl[j] = K[i * MO + j];
    __syncthreads();
    float acc = 0.f;
#pragma unroll 8
    for (int k = 0; k < MO; ++k) acc += kl[k] * H[k * NS + j];
    KH[i * NS + j] = acc;
}

// A_eff = A - KH @ A
__global__ void aeff_kernel(const float* __restrict__ A, const float* __restrict__ KH,
                            float* __restrict__ AE) {
    int i = blockIdx.x, j = threadIdx.x;
    __shared__ float khr[NS];
    khr[j] = KH[i * NS + j];
    __syncthreads();
    float acc = A[i * NS + j];
#pragma unroll 8
    for (int k = 0; k < NS; ++k) acc -= khr[k] * A[k * NS + j];
    AE[i * NS + j] = acc;
}

// dst = src @ src (256x256 squaring)
__global__ void matsq_kernel(const float* __restrict__ src, float* __restrict__ dst) {
    int i = blockIdx.x, j = threadIdx.x;
    __shared__ float row[NS];
    row[j] = src[i * NS + j];
    __syncthreads();
    float acc = 0.f;
#pragma unroll 8
    for (int k = 0; k < NS; ++k) acc += row[k] * src[k * NS + j];
    dst[i * NS + j] = acc;
}

// ---------------- scan kernels ----------------
// Block = 512 threads. thread (i = tid&255, h = tid>>8) holds A_eff[i][h*128 .. h*128+127]
// and K[i][h*64 .. h*64+63] in registers. x lives in LDS (broadcast reads).

template <bool WRITE_OUT>
__launch_bounds__(512, 2)
__global__ void scan_kernel(const float* __restrict__ y, const float* __restrict__ Kmat,
                            const float* __restrict__ AE, const float* __restrict__ cin_buf,
                            float* __restrict__ e_buf, float* __restrict__ out) {
    const int bc = blockIdx.x;
    const int b = bc / CCH, c = bc % CCH;
    const int tid = threadIdx.x;
    const int i = tid & 255, h = tid >> 8;

    __shared__ float x_lds[NS];
    __shared__ float pd[512];
    __shared__ float ytile[32 * MO];  // 16 KB: 32 timesteps of y

    // register-resident half rows
    float areg[128];
    {
        const float4* asrc = (const float4*)(AE + i * NS + h * 128);
#pragma unroll
        for (int k = 0; k < 32; ++k) ((float4*)areg)[k] = asrc[k];
    }
    float kreg[64];
    {
        const float4* ksrc = (const float4*)(Kmat + i * MO + h * 64);
#pragma unroll
        for (int k = 0; k < 16; ++k) ((float4*)kreg)[k] = ksrc[k];
    }

    if (h == 0) {
        if constexpr (WRITE_OUT) {
            x_lds[i] = cin_buf[(b * CCH + c) * NS + i];
        } else {
            x_lds[i] = 0.f;
        }
    }
    __syncthreads();

    const int t0 = c * LL;
    for (int s = 0; s < LL; ++s) {
        if ((s & 31) == 0) {
            // stage next 32 timesteps of y: 4096 floats = 1024 float4
            const float4* ysrc = (const float4*)(y + ((size_t)b * TT + t0 + s) * MO);
            float4* ydst = (float4*)ytile;
            ydst[tid] = ysrc[tid];
            ydst[tid + 512] = ysrc[tid + 512];
            __syncthreads();
        }

        float acc0 = 0.f, acc1 = 0.f, acc2 = 0.f, acc3 = 0.f;
        {
            const float4* xv = (const float4*)(x_lds + (h << 7));
#pragma unroll
            for (int k = 0; k < 32; ++k) {
                float4 xx = xv[k];
                acc0 += areg[4 * k + 0] * xx.x;
                acc1 += areg[4 * k + 1] * xx.y;
                acc2 += areg[4 * k + 2] * xx.z;
                acc3 += areg[4 * k + 3] * xx.w;
            }
        }
        {
            const float4* yv = (const float4*)(ytile + (s & 31) * MO + (h << 6));
#pragma unroll
            for (int k = 0; k < 16; ++k) {
                float4 yy = yv[k];
                acc0 += kreg[4 * k + 0] * yy.x;
                acc1 += kreg[4 * k + 1] * yy.y;
                acc2 += kreg[4 * k + 2] * yy.z;
                acc3 += kreg[4 * k + 3] * yy.w;
            }
        }
        pd[tid] = (acc0 + acc1) + (acc2 + acc3);
        __syncthreads();
        if (h == 0) {
            float xn = pd[i] + pd[i + 256];
            x_lds[i] = xn;
            if constexpr (WRITE_OUT) {
                out[((size_t)b * TT + t0 + s) * NS + i] = xn;
            }
        }
        __syncthreads();
    }

    if constexpr (!WRITE_OUT) {
        if (h == 0) e_buf[(b * CCH + c) * NS + i] = x_lds[i];
    }
}

// Phase B: per batch, serial over chunks: carry_c = ML @ carry_{c-1} + e_c.
// Stores carry INTO each chunk (cin[b][0] = 0).
__global__ void phaseB_kernel(const float* __restrict__ ML, const float* __restrict__ e_buf,
                              float* __restrict__ cin_buf) {
    int b = blockIdx.x, i = threadIdx.x;  // 256 threads
    __shared__ float xl[NS];
    float s = 0.f;
    for (int c = 0; c < CCH; ++c) {
        cin_buf[(b * CCH + c) * NS + i] = s;
        xl[i] = s;
        __syncthreads();
        float acc = e_buf[(b * CCH + c) * NS + i];
        const float4* mr = (const float4*)(ML + i * NS);
        const float4* xv = (const float4*)xl;
#pragma unroll 16
        for (int k = 0; k < 64; ++k) {
            float4 m = mr[k], x = xv[k];
            acc += m.x * x.x + m.y * x.y + m.z * x.z + m.w * x.w;
        }
        __syncthreads();
        s = acc;
    }
}

// ---------------- launcher ----------------

extern "C" void kernel_launch(void* const* d_in, const int* in_sizes, int n_in,
                              void* d_out, int out_size, void* d_ws, size_t ws_size,
                              hipStream_t stream) {
    const float* y = (const float*)d_in[0];
    const float* A = (const float*)d_in[1];
    const float* H = (const float*)d_in[2];
    const float* K = (const float*)d_in[3];
    float* out = (float*)d_out;

    float* ws = (float*)d_ws;
    const size_t MAT = (size_t)NS * NS;  // 65536 floats
    float* KH = ws;
    float* AE = ws + MAT;
    float* Ma = ws + 2 * MAT;
    float* Mb = ws + 3 * MAT;
    float* e_buf = ws + 4 * MAT;    // B*CCH*NS = 65536 floats
    float* cin_buf = ws + 5 * MAT;  // B*CCH*NS

    kh_kernel<<<NS, NS, 0, stream>>>(K, H, KH);
    aeff_kernel<<<NS, NS, 0, stream>>>(A, KH, AE);

    // ML = A_eff^LL  (LL = 256 = 2^8 -> 8 squarings), ping-pong Ma/Mb
    matsq_kernel<<<NS, NS, 0, stream>>>(AE, Ma);   // A^2
    matsq_kernel<<<NS, NS, 0, stream>>>(Ma, Mb);   // A^4
    matsq_kernel<<<NS, NS, 0, stream>>>(Mb, Ma);   // A^8
    matsq_kernel<<<NS, NS, 0, stream>>>(Ma, Mb);   // A^16
    matsq_kernel<<<NS, NS, 0, stream>>>(Mb, Ma);   // A^32
    matsq_kernel<<<NS, NS, 0, stream>>>(Ma, Mb);   // A^64
    matsq_kernel<<<NS, NS, 0, stream>>>(Mb, Ma);   // A^128
    matsq_kernel<<<NS, NS, 0, stream>>>(Ma, Mb);   // A^256 -> Mb

    // Phase A: local chunk scans (end states only)
    scan_kernel<false><<<BB * CCH, 512, 0, stream>>>(y, K, AE, nullptr, e_buf, nullptr);
    // Phase B: chunk carries
    phaseB_kernel<<<BB, NS, 0, stream>>>(Mb, e_buf, cin_buf);
    // Phase C: full scans with correct carry-in, write outputs
    scan_kernel<true><<<BB * CCH, 512, 0, stream>>>(y, K, AE, cin_buf, e_buf, out);
}

// Round 2
// 621.204 us; speedup vs baseline: 1.3555x; 1.3555x over previous
//
#include <hip/hip_runtime.h>

#define NS 256   // n_state
#define MO 128   // n_obs
#define BB 64    // batch
#define TT 1024  // time steps
#define CCH 8    // chunks
#define LL (TT / CCH)  // 128 steps per chunk

// ---------------- small setup kernels ----------------

// KH = K @ H   (256x128 @ 128x256 -> 256x256)
__global__ void kh_kernel(const float* __restrict__ K, const float* __restrict__ H,
                          float* __restrict__ KH) {
    int i = blockIdx.x, j = threadIdx.x;
    __shared__ float kl[MO];
    if (j < MO) kl[j] = K[i * MO + j];
    __syncthreads();
    float acc = 0.f;
#pragma unroll 8
    for (int k = 0; k < MO; ++k) acc += kl[k] * H[k * NS + j];
    KH[i * NS + j] = acc;
}

// A_eff = A - KH @ A
__global__ void aeff_kernel(const float* __restrict__ A, const float* __restrict__ KH,
                            float* __restrict__ AE) {
    int i = blockIdx.x, j = threadIdx.x;
    __shared__ float khr[NS];
    khr[j] = KH[i * NS + j];
    __syncthreads();
    float acc = A[i * NS + j];
#pragma unroll 8
    for (int k = 0; k < NS; ++k) acc -= khr[k] * A[k * NS + j];
    AE[i * NS + j] = acc;
}

// dst = src @ src (256x256 squaring)
__global__ void matsq_kernel(const float* __restrict__ src, float* __restrict__ dst) {
    int i = blockIdx.x, j = threadIdx.x;
    __shared__ float row[NS];
    row[j] = src[i * NS + j];
    __syncthreads();
    float acc = 0.f;
#pragma unroll 8
    for (int k = 0; k < NS; ++k) acc += row[k] * src[k * NS + j];
    dst[i * NS + j] = acc;
}

// ---------------- scan kernels ----------------
// Block = 512 threads. thread (r4 = tid&63, q = tid>>6) owns a 4-row x 32-col
// register tile of A_eff (rows 4*r4..4*r4+3, cols 32q..32q+31) and a 4x16 tile
// of K. x is broadcast-read from LDS (each read feeds 4 FMAs). Partials are
// reduced 8-way through LDS.

template <bool WRITE_OUT>
__launch_bounds__(512, 2)
__global__ void scan_kernel(const float* __restrict__ y, const float* __restrict__ Kmat,
                            const float* __restrict__ AE, const float* __restrict__ cin_buf,
                            float* __restrict__ e_buf, float* __restrict__ out) {
    const int bc = blockIdx.x;
    const int b = bc / CCH, c = bc % CCH;
    const int tid = threadIdx.x;
    const int r4 = tid & 63;   // rows 4*r4 .. 4*r4+3
    const int q = tid >> 6;    // cols 32*q .. 32*q+31 (state), 16*q.. (obs)

    __shared__ float x_lds[NS];          // 1 KB
    __shared__ float pd[8 * NS];         // 8 KB partial sums
    __shared__ float ytile[32 * MO];     // 16 KB: 32 timesteps of y

    // register-resident tiles, fully static indexing
    float4 areg[4][8];
#pragma unroll
    for (int j = 0; j < 4; ++j) {
        const float4* src = (const float4*)(AE + (size_t)(4 * r4 + j) * NS + 32 * q);
#pragma unroll
        for (int k = 0; k < 8; ++k) areg[j][k] = src[k];
    }
    float4 kreg[4][4];
#pragma unroll
    for (int j = 0; j < 4; ++j) {
        const float4* src = (const float4*)(Kmat + (size_t)(4 * r4 + j) * MO + 16 * q);
#pragma unroll
        for (int k = 0; k < 4; ++k) kreg[j][k] = src[k];
    }

    if (tid < NS) {
        x_lds[tid] = WRITE_OUT ? cin_buf[bc * NS + tid] : 0.f;
    }

    const int t0 = c * LL;
    for (int s = 0; s < LL; ++s) {
        if ((s & 31) == 0) {
            __syncthreads();
            const float4* ysrc = (const float4*)(y + ((size_t)b * TT + t0 + s) * MO);
            float4* ydst = (float4*)ytile;
            ydst[tid] = ysrc[tid];
            ydst[tid + 512] = ysrc[tid + 512];
            __syncthreads();
        }

        float acc0 = 0.f, acc1 = 0.f, acc2 = 0.f, acc3 = 0.f;
        {
            const float4* xv = (const float4*)(x_lds + 32 * q);
#pragma unroll
            for (int k = 0; k < 8; ++k) {
                float4 xx = xv[k];
                acc0 += areg[0][k].x * xx.x + areg[0][k].y * xx.y + areg[0][k].z * xx.z + areg[0][k].w * xx.w;
                acc1 += areg[1][k].x * xx.x + areg[1][k].y * xx.y + areg[1][k].z * xx.z + areg[1][k].w * xx.w;
                acc2 += areg[2][k].x * xx.x + areg[2][k].y * xx.y + areg[2][k].z * xx.z + areg[2][k].w * xx.w;
                acc3 += areg[3][k].x * xx.x + areg[3][k].y * xx.y + areg[3][k].z * xx.z + areg[3][k].w * xx.w;
            }
        }
        {
            const float4* yv = (const float4*)(ytile + (s & 31) * MO + 16 * q);
#pragma unroll
            for (int k = 0; k < 4; ++k) {
                float4 yy = yv[k];
                acc0 += kreg[0][k].x * yy.x + kreg[0][k].y * yy.y + kreg[0][k].z * yy.z + kreg[0][k].w * yy.w;
                acc1 += kreg[1][k].x * yy.x + kreg[1][k].y * yy.y + kreg[1][k].z * yy.z + kreg[1][k].w * yy.w;
                acc2 += kreg[2][k].x * yy.x + kreg[2][k].y * yy.y + kreg[2][k].z * yy.z + kreg[2][k].w * yy.w;
                acc3 += kreg[3][k].x * yy.x + kreg[3][k].y * yy.y + kreg[3][k].z * yy.z + kreg[3][k].w * yy.w;
            }
        }
        *(float4*)(pd + q * NS + 4 * r4) = make_float4(acc0, acc1, acc2, acc3);
        __syncthreads();

        if (tid < NS) {
            float xn = ((pd[0 * NS + tid] + pd[1 * NS + tid]) + (pd[2 * NS + tid] + pd[3 * NS + tid])) +
                       ((pd[4 * NS + tid] + pd[5 * NS + tid]) + (pd[6 * NS + tid] + pd[7 * NS + tid]));
            x_lds[tid] = xn;
            if constexpr (WRITE_OUT) {
                out[((size_t)b * TT + t0 + s) * NS + tid] = xn;
            }
        }
        __syncthreads();
    }

    if constexpr (!WRITE_OUT) {
        if (tid < NS) e_buf[bc * NS + tid] = x_lds[tid];
    }
}

// Phase B: per batch, serial over chunks: carry_c = ML @ carry_{c-1} + e_c.
// Stores carry INTO each chunk (cin[b][0] = 0).
__global__ void phaseB_kernel(const float* __restrict__ ML, const float* __restrict__ e_buf,
                              float* __restrict__ cin_buf) {
    int b = blockIdx.x, i = threadIdx.x;  // 256 threads
    __shared__ float xl[NS];
    float s = 0.f;
    for (int c = 0; c < CCH; ++c) {
        cin_buf[(b * CCH + c) * NS + i] = s;
        xl[i] = s;
        __syncthreads();
        float acc = e_buf[(b * CCH + c) * NS + i];
        const float4* mr = (const float4*)(ML + (size_t)i * NS);
        const float4* xv = (const float4*)xl;
#pragma unroll 16
        for (int k = 0; k < 64; ++k) {
            float4 m = mr[k], x = xv[k];
            acc += m.x * x.x + m.y * x.y + m.z * x.z + m.w * x.w;
        }
        __syncthreads();
        s = acc;
    }
}

// ---------------- launcher ----------------

extern "C" void kernel_launch(void* const* d_in, const int* in_sizes, int n_in,
                              void* d_out, int out_size, void* d_ws, size_t ws_size,
                              hipStream_t stream) {
    const float* y = (const float*)d_in[0];
    const float* A = (const float*)d_in[1];
    const float* H = (const float*)d_in[2];
    const float* K = (const float*)d_in[3];
    float* out = (float*)d_out;

    float* ws = (float*)d_ws;
    const size_t MAT = (size_t)NS * NS;  // 65536 floats
    float* KH = ws;
    float* AE = ws + MAT;
    float* Ma = ws + 2 * MAT;
    float* Mb = ws + 3 * MAT;
    float* e_buf = ws + 4 * MAT;    // BB*CCH*NS = 131072 floats (2 MAT)
    float* cin_buf = ws + 6 * MAT;  // BB*CCH*NS

    kh_kernel<<<NS, NS, 0, stream>>>(K, H, KH);
    aeff_kernel<<<NS, NS, 0, stream>>>(A, KH, AE);

    // ML = A_eff^LL  (LL = 128 = 2^7 -> 7 squarings), ping-pong Ma/Mb
    matsq_kernel<<<NS, NS, 0, stream>>>(AE, Ma);   // A^2
    matsq_kernel<<<NS, NS, 0, stream>>>(Ma, Mb);   // A^4
    matsq_kernel<<<NS, NS, 0, stream>>>(Mb, Ma);   // A^8
    matsq_kernel<<<NS, NS, 0, stream>>>(Ma, Mb);   // A^16
    matsq_kernel<<<NS, NS, 0, stream>>>(Mb, Ma);   // A^32
    matsq_kernel<<<NS, NS, 0, stream>>>(Ma, Mb);   // A^64
    matsq_kernel<<<NS, NS, 0, stream>>>(Mb, Ma);   // A^128 -> Ma

    // Phase A: local chunk scans (end states only)
    scan_kernel<false><<<BB * CCH, 512, 0, stream>>>(y, K, AE, nullptr, e_buf, nullptr);
    // Phase B: chunk carries
    phaseB_kernel<<<BB, NS, 0, stream>>>(Ma, e_buf, cin_buf);
    // Phase C: full scans with correct carry-in, write outputs
    scan_kernel<true><<<BB * CCH, 512, 0, stream>>>(y, K, AE, cin_buf, e_buf, out);
}

// Round 3
// 249.541 us; speedup vs baseline: 3.3745x; 2.4894x over previous
//
#include <hip/hip_runtime.h>

#define NS 256    // n_state
#define MO 128    // n_obs
#define BB 64     // batch
#define TT 1024   // time steps
#define CCH 64    // chunks per batch
#define SS 16     // steps per chunk

typedef short s16x8 __attribute__((ext_vector_type(8)));
typedef float f32x4 __attribute__((ext_vector_type(4)));
typedef unsigned int uint;
typedef unsigned short ushort;

__device__ __forceinline__ ushort f2bf(float x) {
    uint u = __float_as_uint(x);
    uint r = (u + 0x7fffu + ((u >> 16) & 1u)) >> 16;
    return (ushort)r;
}
__device__ __forceinline__ float bf2f(ushort h) { return __uint_as_float(((uint)h) << 16); }

__device__ __forceinline__ f32x4 mfma16(s16x8 a, s16x8 b, f32x4 c) {
    return __builtin_amdgcn_mfma_f32_16x16x32_bf16(a, b, c, 0, 0, 0);
}

// ---------------- small setup kernels (fp32, proven) ----------------

__global__ void kh_kernel(const float* __restrict__ K, const float* __restrict__ H,
                          float* __restrict__ KH) {
    int i = blockIdx.x, j = threadIdx.x;
    __shared__ float kl[MO];
    if (j < MO) kl[j] = K[i * MO + j];
    __syncthreads();
    float acc = 0.f;
#pragma unroll 8
    for (int k = 0; k < MO; ++k) acc += kl[k] * H[k * NS + j];
    KH[i * NS + j] = acc;
}

__global__ void aeff_kernel(const float* __restrict__ A, const float* __restrict__ KH,
                            float* __restrict__ AE) {
    int i = blockIdx.x, j = threadIdx.x;
    __shared__ float khr[NS];
    khr[j] = KH[i * NS + j];
    __syncthreads();
    float acc = A[i * NS + j];
#pragma unroll 8
    for (int k = 0; k < NS; ++k) acc -= khr[k] * A[k * NS + j];
    AE[i * NS + j] = acc;
}

__global__ void matsq_kernel(const float* __restrict__ src, float* __restrict__ dst) {
    int i = blockIdx.x, j = threadIdx.x;
    __shared__ float row[NS];
    row[j] = src[i * NS + j];
    __syncthreads();
    float acc = 0.f;
#pragma unroll 8
    for (int k = 0; k < NS; ++k) acc += row[k] * src[k * NS + j];
    dst[i * NS + j] = acc;
}

// Convert 3 fp32 matrices to bf16 hi/lo pairs.
__global__ void conv_kernel(const float* __restrict__ AE, const float* __restrict__ M,
                            const float* __restrict__ M2,
                            ushort* __restrict__ aeh, ushort* __restrict__ ael,
                            ushort* __restrict__ mh, ushort* __restrict__ ml,
                            ushort* __restrict__ m2h, ushort* __restrict__ m2l) {
    int i = (blockIdx.x & 255) * 256 + threadIdx.x;
    int mat = blockIdx.x >> 8;
    const float* src = (mat == 0) ? AE : ((mat == 1) ? M : M2);
    ushort* dh = (mat == 0) ? aeh : ((mat == 1) ? mh : m2h);
    ushort* dl = (mat == 0) ? ael : ((mat == 1) ? ml : m2l);
    float v = src[i];
    ushort hi = f2bf(v);
    dh[i] = hi;
    dl[i] = f2bf(v - bf2f(hi));
}

// ---------------- U = Y @ K^T  (MFMA, bf16 hi/lo, register-only) ----------------
// Y: [B*T, 128] fp32 -> U: [B*T, 256] fp32 (written into d_out).

__launch_bounds__(512, 2)
__global__ void ugemm_kernel(const float* __restrict__ y, const float* __restrict__ K,
                             float* __restrict__ U) {
    const int tid = threadIdx.x, blk = blockIdx.x;
    const int w = tid >> 6, l = tid & 63, lr = l & 15, lg = l >> 4;

    // B-operand: B[k, j] = K[j, k]; lane holds K[16t+lr, 32q+8lg .. +7]
    s16x8 KBh[2][4], KBl[2][4];
#pragma unroll
    for (int t2 = 0; t2 < 2; ++t2) {
        int row = 16 * (2 * w + t2) + lr;
#pragma unroll
        for (int q = 0; q < 4; ++q) {
            int off = row * MO + 32 * q + 8 * lg;
            float4 a = *(const float4*)(K + off);
            float4 b = *(const float4*)(K + off + 4);
            s16x8 vh, vl;
            float f;
            ushort h;
            f = a.x; h = f2bf(f); vh[0] = (short)h; vl[0] = (short)f2bf(f - bf2f(h));
            f = a.y; h = f2bf(f); vh[1] = (short)h; vl[1] = (short)f2bf(f - bf2f(h));
            f = a.z; h = f2bf(f); vh[2] = (short)h; vl[2] = (short)f2bf(f - bf2f(h));
            f = a.w; h = f2bf(f); vh[3] = (short)h; vl[3] = (short)f2bf(f - bf2f(h));
            f = b.x; h = f2bf(f); vh[4] = (short)h; vl[4] = (short)f2bf(f - bf2f(h));
            f = b.y; h = f2bf(f); vh[5] = (short)h; vl[5] = (short)f2bf(f - bf2f(h));
            f = b.z; h = f2bf(f); vh[6] = (short)h; vl[6] = (short)f2bf(f - bf2f(h));
            f = b.w; h = f2bf(f); vh[7] = (short)h; vl[7] = (short)f2bf(f - bf2f(h));
            KBh[t2][q] = vh; KBl[t2][q] = vl;
        }
    }

#pragma unroll 1
    for (int it = 0; it < 16; ++it) {
        int rt = blk * 16 + it;
        s16x8 Ah[4], Al[4];
#pragma unroll
        for (int q = 0; q < 4; ++q) {
            int off = (rt * 16 + lr) * MO + 32 * q + 8 * lg;
            float4 a = *(const float4*)(y + off);
            float4 b = *(const float4*)(y + off + 4);
            s16x8 vh, vl;
            float f;
            ushort h;
            f = a.x; h = f2bf(f); vh[0] = (short)h; vl[0] = (short)f2bf(f - bf2f(h));
            f = a.y; h = f2bf(f); vh[1] = (short)h; vl[1] = (short)f2bf(f - bf2f(h));
            f = a.z; h = f2bf(f); vh[2] = (short)h; vl[2] = (short)f2bf(f - bf2f(h));
            f = a.w; h = f2bf(f); vh[3] = (short)h; vl[3] = (short)f2bf(f - bf2f(h));
            f = b.x; h = f2bf(f); vh[4] = (short)h; vl[4] = (short)f2bf(f - bf2f(h));
            f = b.y; h = f2bf(f); vh[5] = (short)h; vl[5] = (short)f2bf(f - bf2f(h));
            f = b.z; h = f2bf(f); vh[6] = (short)h; vl[6] = (short)f2bf(f - bf2f(h));
            f = b.w; h = f2bf(f); vh[7] = (short)h; vl[7] = (short)f2bf(f - bf2f(h));
            Ah[q] = vh; Al[q] = vl;
        }
        f32x4 acc0 = {0.f, 0.f, 0.f, 0.f};
        f32x4 acc1 = {0.f, 0.f, 0.f, 0.f};
#pragma unroll
        for (int q = 0; q < 4; ++q) {
            acc0 = mfma16(Ah[q], KBh[0][q], acc0);
            acc0 = mfma16(Al[q], KBh[0][q], acc0);
            acc0 = mfma16(Ah[q], KBl[0][q], acc0);
            acc1 = mfma16(Ah[q], KBh[1][q], acc1);
            acc1 = mfma16(Al[q], KBh[1][q], acc1);
            acc1 = mfma16(Ah[q], KBl[1][q], acc1);
        }
#pragma unroll
        for (int i = 0; i < 4; ++i) {
            int orow = rt * 16 + 4 * lg + i;
            U[orow * NS + 32 * w + lr] = acc0[i];
            U[orow * NS + 32 * w + 16 + lr] = acc1[i];
        }
    }
}

// ---------------- MFMA serial scan: 16 rows/block, matrix in register B-frags ----------------
// MODE 0 (A):  local chunk scans from 0, S=16, store chunk-end e.          grid 256
// MODE 1 (Ba): local superchunk scans of e from 0, S=8, store e2.          grid 32
// MODE 2 (Bb): superchunk carry scan over e2, S=8, write c2[b,g+1].        grid 4
// MODE 3 (Bc): chunk carries from c2 over e, S=8, write cbuf[b,8g+j+1].    grid 32
// MODE 4 (C):  final scans from cbuf over u, S=16, write out each step.    grid 256

template <int MODE>
__launch_bounds__(512, 2)
__global__ void scan16_kernel(const ushort* __restrict__ mh, const ushort* __restrict__ ml,
                              const float* u, const float* __restrict__ cin,
                              float* wout, float* __restrict__ eout) {
    constexpr int S = (MODE == 0 || MODE == 4) ? SS : 8;
    const int tid = threadIdx.x;
    const int blk = blockIdx.x;
    const int w = tid >> 6;
    const int l = tid & 63;
    const int lr = l & 15;
    const int lg = l >> 4;

    __shared__ ushort xh_s[16 * NS];
    __shared__ ushort xl_s[16 * NS];

    // u row base for row index m (step stride is 256 floats)
    auto ubase = [&](int m) -> long {
        if constexpr (MODE == 0 || MODE == 4) {
            int cc = blk >> 2, b = (blk & 3) * 16 + m;
            return ((long)b * TT + cc * SS) * NS;
        } else if constexpr (MODE == 1 || MODE == 3) {
            int rid = blk * 16 + m;
            int b = rid >> 3, g = rid & 7;
            return ((long)b * 64 + g * 8) * NS;
        } else {
            int b = blk * 16 + m;
            return (long)b * 8 * NS;
        }
    };

    // ---- static matrix fragments (bf16 hi/lo), 128 VGPR ----
    s16x8 Bh[2][8], Bl[2][8];
#pragma unroll
    for (int t2 = 0; t2 < 2; ++t2) {
        int row = 16 * (2 * w + t2) + lr;
#pragma unroll
        for (int q = 0; q < 8; ++q) {
            int off = row * NS + 32 * q + 8 * lg;
            Bh[t2][q] = *(const s16x8*)(mh + off);
            Bl[t2][q] = *(const s16x8*)(ml + off);
        }
    }

    // ---- init x state (carry-in or zero), plus zero-row extras ----
#pragma unroll
    for (int jj = 0; jj < 8; ++jj) {
        int idx = jj * 512 + tid;  // 0..4095
        int m = idx >> 8, col = idx & 255;
        float xv = 0.f;
        if constexpr (MODE == 3) {
            int rid = blk * 16 + m;
            int b = rid >> 3, g = rid & 7;
            xv = cin[(b * 8 + g) * NS + col];
            if (g == 0) wout[(long)b * 64 * NS + col] = 0.f;  // cbuf[b,0] = 0
        } else if constexpr (MODE == 4) {
            int cc = blk >> 2, b = (blk & 3) * 16 + m;
            xv = cin[(b * 64 + cc) * NS + col];
        } else if constexpr (MODE == 2) {
            int b = blk * 16 + m;
            wout[(long)b * 8 * NS + col] = 0.f;  // c2[b,0] = 0
        }
        ushort hi = f2bf(xv);
        ushort lo = f2bf(xv - bf2f(hi));
        int sidx = (m * NS + col) ^ ((m & 7) << 3);
        xh_s[sidx] = hi;
        xl_s[sidx] = lo;
    }

    const int col0 = 32 * w + lr;
    const int col1 = col0 + 16;

    // prefetch u for step 0
    float up0[4], up1[4];
#pragma unroll
    for (int i = 0; i < 4; ++i) {
        int m = 4 * lg + i;
        long ub = ubase(m);
        up0[i] = u[ub + col0];
        up1[i] = u[ub + col1];
    }
    __syncthreads();

    for (int s = 0; s < S; ++s) {
        f32x4 acc0, acc1;
        acc0[0] = up0[0]; acc0[1] = up0[1]; acc0[2] = up0[2]; acc0[3] = up0[3];
        acc1[0] = up1[0]; acc1[1] = up1[1]; acc1[2] = up1[2]; acc1[3] = up1[3];

#pragma unroll
        for (int q = 0; q < 8; ++q) {
            int ridx = (lr * NS + 32 * q + 8 * lg) ^ ((lr & 7) << 3);
            s16x8 xh = *(const s16x8*)&xh_s[ridx];
            s16x8 xl = *(const s16x8*)&xl_s[ridx];
            acc0 = mfma16(xh, Bh[0][q], acc0);
            acc0 = mfma16(xl, Bh[0][q], acc0);
            acc0 = mfma16(xh, Bl[0][q], acc0);
            acc1 = mfma16(xh, Bh[1][q], acc1);
            acc1 = mfma16(xl, Bh[1][q], acc1);
            acc1 = mfma16(xh, Bl[1][q], acc1);
        }

        // prefetch u for next step
        if (s + 1 < S) {
#pragma unroll
            for (int i = 0; i < 4; ++i) {
                int m = 4 * lg + i;
                long ub = ubase(m) + (long)(s + 1) * NS;
                up0[i] = u[ub + col0];
                up1[i] = u[ub + col1];
            }
        }

        // stores
        if constexpr (MODE == 2) {
            if (s < 7) {
#pragma unroll
                for (int i = 0; i < 4; ++i) {
                    int m = 4 * lg + i;
                    int b = blk * 16 + m;
                    long wb = ((long)b * 8 + s + 1) * NS;
                    wout[wb + col0] = acc0[i];
                    wout[wb + col1] = acc1[i];
                }
            }
        } else if constexpr (MODE == 3) {
#pragma unroll
            for (int i = 0; i < 4; ++i) {
                int m = 4 * lg + i;
                int rid = blk * 16 + m;
                int b = rid >> 3, g = rid & 7;
                int kk = 8 * g + s + 1;
                if (kk < 64) {
                    long wb = ((long)b * 64 + kk) * NS;
                    wout[wb + col0] = acc0[i];
                    wout[wb + col1] = acc1[i];
                }
            }
        } else if constexpr (MODE == 4) {
#pragma unroll
            for (int i = 0; i < 4; ++i) {
                int m = 4 * lg + i;
                long wb = ubase(m) + (long)s * NS;
                wout[wb + col0] = acc0[i];
                wout[wb + col1] = acc1[i];
            }
        }
        if constexpr (MODE == 0 || MODE == 1) {
            if (s == S - 1) {
#pragma unroll
                for (int i = 0; i < 4; ++i) {
                    int m = 4 * lg + i;
                    long eb;
                    if constexpr (MODE == 0) {
                        int cc = blk >> 2, b = (blk & 3) * 16 + m;
                        eb = ((long)b * 64 + cc) * NS;
                    } else {
                        eb = (long)(blk * 16 + m) * NS;
                    }
                    eout[eb + col0] = acc0[i];
                    eout[eb + col1] = acc1[i];
                }
            }
        }

        __syncthreads();  // all LDS reads of this step done

        // write new x (bf16 hi/lo) for next step
#pragma unroll
        for (int i = 0; i < 4; ++i) {
            int m = 4 * lg + i;
            {
                ushort hi = f2bf(acc0[i]);
                ushort lo = f2bf(acc0[i] - bf2f(hi));
                int wi = (m * NS + col0) ^ ((m & 7) << 3);
                xh_s[wi] = hi;
                xl_s[wi] = lo;
            }
            {
                ushort hi = f2bf(acc1[i]);
                ushort lo = f2bf(acc1[i] - bf2f(hi));
                int wi = (m * NS + col1) ^ ((m & 7) << 3);
                xh_s[wi] = hi;
                xl_s[wi] = lo;
            }
        }
        __syncthreads();
    }
}

// ---------------- launcher ----------------

extern "C" void kernel_launch(void* const* d_in, const int* in_sizes, int n_in,
                              void* d_out, int out_size, void* d_ws, size_t ws_size,
                              hipStream_t stream) {
    const float* y = (const float*)d_in[0];
    const float* A = (const float*)d_in[1];
    const float* H = (const float*)d_in[2];
    const float* K = (const float*)d_in[3];
    float* out = (float*)d_out;

    float* ws = (float*)d_ws;
    const long MAT = (long)NS * NS;  // 65536 floats
    float* KH = ws + 0 * MAT;
    float* AE = ws + 1 * MAT;
    float* W0 = ws + 2 * MAT;  // A^2
    float* W1 = ws + 3 * MAT;  // A^4
    float* W2 = ws + 4 * MAT;  // A^8
    float* W3 = ws + 5 * MAT;  // A^16  (M)
    float* W4 = ws + 6 * MAT;  // A^32
    float* W5 = ws + 7 * MAT;  // A^64
    float* W6 = ws + 8 * MAT;  // A^128 (M2)
    ushort* aeh = (ushort*)(ws + 9 * MAT);
    ushort* ael = aeh + MAT;
    ushort* mh = ael + MAT;
    ushort* ml = mh + MAT;
    ushort* m2h = ml + MAT;
    ushort* m2l = m2h + MAT;   // ends at float offset 12*MAT
    float* e_buf = ws + 12 * MAT;   // [64][64][256] = 16 MAT
    float* e2 = ws + 28 * MAT;      // [64][8][256]  = 2 MAT
    float* c2 = ws + 30 * MAT;      // [64][8][256]  = 2 MAT
    float* cbuf = ws + 32 * MAT;    // [64][64][256] = 16 MAT -> ends 48 MAT (12.6 MB)

    float* U = out;  // u = y@K^T lives in d_out; phase C overwrites in place

    kh_kernel<<<NS, NS, 0, stream>>>(K, H, KH);
    aeff_kernel<<<NS, NS, 0, stream>>>(A, KH, AE);
    matsq_kernel<<<NS, NS, 0, stream>>>(AE, W0);
    matsq_kernel<<<NS, NS, 0, stream>>>(W0, W1);
    matsq_kernel<<<NS, NS, 0, stream>>>(W1, W2);
    matsq_kernel<<<NS, NS, 0, stream>>>(W2, W3);
    matsq_kernel<<<NS, NS, 0, stream>>>(W3, W4);
    matsq_kernel<<<NS, NS, 0, stream>>>(W4, W5);
    matsq_kernel<<<NS, NS, 0, stream>>>(W5, W6);
    conv_kernel<<<768, 256, 0, stream>>>(AE, W3, W6, aeh, ael, mh, ml, m2h, m2l);

    ugemm_kernel<<<256, 512, 0, stream>>>(y, K, U);

    // Phase A: local chunk scans -> e
    scan16_kernel<0><<<256, 512, 0, stream>>>(aeh, ael, U, nullptr, nullptr, e_buf);
    // Phase Ba: superchunk local scans of e -> e2
    scan16_kernel<1><<<32, 512, 0, stream>>>(mh, ml, e_buf, nullptr, nullptr, e2);
    // Phase Bb: superchunk carry scan -> c2
    scan16_kernel<2><<<4, 512, 0, stream>>>(m2h, m2l, e2, nullptr, c2, nullptr);
    // Phase Bc: chunk carries -> cbuf
    scan16_kernel<3><<<32, 512, 0, stream>>>(mh, ml, e_buf, c2, cbuf, nullptr);
    // Phase C: final scans, write out
    scan16_kernel<4><<<256, 512, 0, stream>>>(aeh, ael, U, cbuf, out, nullptr);
}